// Round 1
// baseline (2913.687 us; speedup 1.0000x reference)
//
#include <hip/hip_runtime.h>
#include <stdint.h>

typedef unsigned int u32;
typedef unsigned short u16;
typedef unsigned long long u64;
typedef __attribute__((ext_vector_type(8))) short short8;
typedef __attribute__((ext_vector_type(4))) float f32x4;

#define NB 64
#define NS 512
#define NI 512
#define NH 1024

// bf16 +inf in all 4 slots: unreachable for |h|<=1, so it is a safe "not yet
// written" sentinel for published h granules.
#define SENT 0x7F807F807F807F80ULL

// ---- workspace byte offsets ----
#define OFF_AT    0ULL          // inputs transposed->bf16, swizzled: [32768][512] bf16
#define OFF_H     0ULL          // h image, 4 rotating buffers [64][1024] bf16 (aliases AT;
                                // GRU_init_h runs AFTER GRU_xproj, AT is dead by then)
#define OFF_WI    33554432ULL   // input weights bf16 swizzled: [3][1024][512]
#define OFF_WH    36700160ULL   // recurrent weights, MFMA B-frag order: [3][64][32][64][8]
#define OFF_XR    42991616ULL   // xr [512 s][1024 h][64 b] bf16 (transposed pack)
#define OFF_XZ    110100480ULL  // xz
#define OFF_XN    177209344ULL  // xn

__device__ __forceinline__ u16 f2bf(float f){
  u32 u = __float_as_uint(f);
  u += 0x7fffu + ((u >> 16) & 1u);
  return (u16)(u >> 16);
}
__device__ __forceinline__ float bf2f(u16 h){
  return __uint_as_float(((u32)h) << 16);
}
__device__ __forceinline__ float sigm(float x){ return 1.0f / (1.0f + __expf(-x)); }
__device__ __forceinline__ float tanhf_(float x){
  float a = fabsf(x);
  float e = __expf(-2.0f * a);
  float t = (1.0f - e) / (1.0f + e);
  return copysignf(t, x);
}
__device__ __forceinline__ void gl_lds16(const void* g, void* l){
  __builtin_amdgcn_global_load_lds((const __attribute__((address_space(1))) void*)g,
                                   (__attribute__((address_space(3))) void*)l, 16, 0, 0);
}
__device__ __forceinline__ uint4 pack8(float4 a, float4 b){
  uint4 o;
  o.x = (u32)f2bf(a.x) | ((u32)f2bf(a.y) << 16);
  o.y = (u32)f2bf(a.z) | ((u32)f2bf(a.w) << 16);
  o.z = (u32)f2bf(b.x) | ((u32)f2bf(b.y) << 16);
  o.w = (u32)f2bf(b.z) | ((u32)f2bf(b.w) << 16);
  return o;
}
// MALL-coherent (agent-scope, L2-bypassing) atomics
__device__ __forceinline__ u64 ald8(const u64* p){
  return __hip_atomic_load(p, __ATOMIC_RELAXED, __HIP_MEMORY_SCOPE_AGENT);
}
__device__ __forceinline__ void ast8(u64* p, u64 v){
  __hip_atomic_store(p, v, __ATOMIC_RELAXED, __HIP_MEMORY_SCOPE_AGENT);
}

// ---------------- prep kernels ----------------

// inputs [b][s][i] f32 -> AT [m=s*64+b][i] bf16, per-row 16B-block XOR swizzle
__global__ void GRU_prep_at(const float* __restrict__ in, u16* __restrict__ at){
  int idx = blockIdx.x * 256 + threadIdx.x;      // 2,097,152 total
  int m = idx >> 6, k8 = idx & 63;
  int s = m >> 6, b = m & 63;
  const float* src = in + (((size_t)b * NS + s) * NI + k8 * 8);
  float4 f0 = *(const float4*)(src);
  float4 f1 = *(const float4*)(src + 4);
  uint4 o = pack8(f0, f1);
  *(uint4*)((char*)at + (size_t)m * 1024 + ((k8 * 16) ^ ((m & 7) << 4))) = o;
}

// w_i{r,z,n} [h][i] f32 -> WI [g][h][i] bf16 swizzled
__global__ void GRU_prep_wi(const float* __restrict__ w0, const float* __restrict__ w1,
                            const float* __restrict__ w2, u16* __restrict__ wi){
  int idx = blockIdx.x * 256 + threadIdx.x;      // 196,608 total
  int g = idx >> 16;
  int rem = idx & 65535;
  int h = rem >> 6, k8 = rem & 63;
  const float* wsrc = (g == 0) ? w0 : ((g == 1) ? w1 : w2);
  const float* src = wsrc + (size_t)h * NI + k8 * 8;
  float4 f0 = *(const float4*)(src);
  float4 f1 = *(const float4*)(src + 4);
  uint4 o = pack8(f0, f1);
  *(uint4*)((char*)wi + ((size_t)(g * NH + h)) * 1024 + ((k8 * 16) ^ ((h & 7) << 4))) = o;
}

// w_h{r,z,n} [f][k] f32 -> WH in MFMA B-fragment order: [g][ftile(64)][kc(32)][lane(64)][8 bf16]
__global__ void GRU_prep_wh(const float* __restrict__ w0, const float* __restrict__ w1,
                            const float* __restrict__ w2, u16* __restrict__ wh){
  int idx = blockIdx.x * 256 + threadIdx.x;      // 393,216 total
  int l = idx & 63;
  int kc = (idx >> 6) & 31;
  int t = idx >> 11;            // g*64 + ftile
  int g = t >> 6, ft = t & 63;
  const float* wsrc = (g == 0) ? w0 : ((g == 1) ? w1 : w2);
  int f = ft * 16 + (l & 15);
  int k = kc * 32 + ((l >> 4) * 8);
  const float* src = wsrc + (size_t)f * NH + k;
  float4 f0 = *(const float4*)(src);
  float4 f1 = *(const float4*)(src + 4);
  uint4 o = pack8(f0, f1);
  *(uint4*)((char*)wh + (size_t)idx * 16) = o;
}

// hidden[0] f32 -> h buffer 0 (bf16, LINEAR [64][1024]); buffers 1..3 <- sentinel
// NOTE: launched AFTER GRU_xproj (h image aliases the AT region).
__global__ void GRU_init_h(const float* __restrict__ h0, u16* __restrict__ hImg){
  int gt = blockIdx.x * 256 + threadIdx.x;       // 8192 threads
  int b = gt >> 7, k8 = gt & 127;
  const float* src = h0 + (size_t)b * NH + k8 * 8;
  float4 f0 = *(const float4*)(src);
  float4 f1 = *(const float4*)(src + 4);
  uint4 o = pack8(f0, f1);
  *(uint4*)((char*)hImg + (size_t)b * 2048 + k8 * 16) = o;
  u64* hb = (u64*)hImg;
  #pragma unroll
  for (int qb = 1; qb <= 3; ++qb){
    hb[(size_t)qb * 16384 + (size_t)gt * 2 + 0] = SENT;
    hb[(size_t)qb * 16384 + (size_t)gt * 2 + 1] = SENT;
  }
}

// ---------------- input-projection GEMM ----------------
// C[m][n] = sum_k AT[m][k]*WI[g][n][k] + bias, stored bf16 TRANSPOSED to xg[s][n][b]
__global__ __launch_bounds__(256) void GRU_xproj(const u16* __restrict__ AT,
    const u16* __restrict__ WI,
    const float* __restrict__ bi0, const float* __restrict__ bi1, const float* __restrict__ bi2,
    u16* __restrict__ xr, u16* __restrict__ xz, u16* __restrict__ xn){
  __shared__ __align__(16) char lds[32768];     // A: [0,16K), B: [16K,32K)
  int tid = threadIdx.x;
  int l = tid & 63, w = tid >> 6;
  int c = l & 15, q = l >> 4;
  int mt = blockIdx.x, nt = blockIdx.y, g = blockIdx.z;
  const float* bi = (g == 0) ? bi0 : ((g == 1) ? bi1 : bi2);
  u16* xg = (g == 0) ? xr : ((g == 1) ? xz : xn);
  int m0 = mt * 128, n0 = nt * 128;
  int wm = w >> 1, wn = w & 1;

  f32x4 acc[4][4];
  #pragma unroll
  for (int i = 0; i < 4; ++i)
    #pragma unroll
    for (int j = 0; j < 4; ++j) acc[i][j] = (f32x4)0.0f;

  const char* Asrc = (const char*)AT + (size_t)m0 * 1024;
  const char* Bsrc = (const char*)WI + ((size_t)g * NH + n0) * 1024;

  for (int kt = 0; kt < 8; ++kt){
    #pragma unroll
    for (int r2 = 0; r2 < 4; ++r2){
      int idx = r2 * 256 + tid;
      int row = idx >> 3, k8 = idx & 7;
      gl_lds16(Asrc + (size_t)row * 1024 + kt * 128 + k8 * 16, lds + ((idx >> 6) << 10));
    }
    #pragma unroll
    for (int r2 = 0; r2 < 4; ++r2){
      int idx = r2 * 256 + tid;
      int row = idx >> 3, k8 = idx & 7;
      gl_lds16(Bsrc + (size_t)row * 1024 + kt * 128 + k8 * 16, lds + 16384 + ((idx >> 6) << 10));
    }
    __syncthreads();
    #pragma unroll
    for (int kk = 0; kk < 2; ++kk){
      short8 af[4], bf[4];
      int kb = kk * 64 + q * 16;
      #pragma unroll
      for (int mf = 0; mf < 4; ++mf){
        int row = wm * 64 + mf * 16 + c;
        af[mf] = *(const short8*)(lds + row * 128 + (kb ^ ((row & 7) << 4)));
      }
      #pragma unroll
      for (int nf = 0; nf < 4; ++nf){
        int row = wn * 64 + nf * 16 + c;
        bf[nf] = *(const short8*)(lds + 16384 + row * 128 + (kb ^ ((row & 7) << 4)));
      }
      #pragma unroll
      for (int mf = 0; mf < 4; ++mf)
        #pragma unroll
        for (int nf = 0; nf < 4; ++nf)
          acc[mf][nf] = __builtin_amdgcn_mfma_f32_16x16x32_bf16(af[mf], bf[nf], acc[mf][nf], 0, 0, 0);
    }
    __syncthreads();
  }
  // epilogue: add bias, cvt bf16, store TRANSPOSED [s][n][b], 8B per (mf,nf)
  int sidx = mt * 2 + wm;             // row>>6 (mf*16+q*4+j <= 63)
  #pragma unroll
  for (int nf = 0; nf < 4; ++nf){
    int n = n0 + wn * 64 + nf * 16 + c;
    float bv = bi[n];
    #pragma unroll
    for (int mf = 0; mf < 4; ++mf){
      int b0 = mf * 16 + q * 4;       // batch of j=0
      u32 w0 = (u32)f2bf(acc[mf][nf][0] + bv) | ((u32)f2bf(acc[mf][nf][1] + bv) << 16);
      u32 w1 = (u32)f2bf(acc[mf][nf][2] + bv) | ((u32)f2bf(acc[mf][nf][3] + bv) << 16);
      uint2 o; o.x = w0; o.y = w1;
      *(uint2*)(xg + ((size_t)sidx * NH + n) * NB + b0) = o;
    }
  }
}

// ---------------- persistent recurrent kernel ----------------
// 64 WGs = (bg 0..3: 16 batches) x (fg 0..15: 64 features). 4 waves.
// Flagless sentinel protocol: producers store h granules (8B atomic, agent
// scope); consumers poll the DATA granules directly until != SENT. The load
// that detects publication IS the data load -> ~2 fewer MALL round trips per
// step than flag-based sync. 4 rotating buffers; buffer (s-1)&3 is re-cleared
// to SENT during step s (poll pass of step s proves all waves finished
// reading it), and is republished at step s+2, repolled at step s+3.
__global__ __launch_bounds__(256, 1) void GRU_rec(const u16* __restrict__ WH,
    const u16* __restrict__ xr, const u16* __restrict__ xz, const u16* __restrict__ xn,
    const float* __restrict__ bhr, const float* __restrict__ bhz, const float* __restrict__ bhn,
    const float* __restrict__ h0, u16* __restrict__ hImg, float* __restrict__ out){
  __shared__ __align__(16) char hl[68096];      // staging 2x32768 @0, wave tiles 4x640 @65536
  int tid = threadIdx.x;
  int l = tid & 63, w = tid >> 6;
  int wg = blockIdx.x;
  int bg = wg >> 4, fg = wg & 15;
  int c = l & 15, q = l >> 4;

  // weights -> registers: bw[gate][kc]  (384 regs, AGPR-backed)
  short8 bw[3][32];
  {
    const short8* base = (const short8*)WH;
    int ft = fg * 4 + w;
    #pragma unroll
    for (int g = 0; g < 3; ++g)
      #pragma unroll
      for (int kc = 0; kc < 32; ++kc)
        bw[g][kc] = base[(size_t)((g * 64 + ft) * 32 + kc) * 64 + l];
  }

  int frow = fg * 64 + w * 16 + c;              // this lane's feature
  int brow = bg * 16 + q * 4;                   // this lane's first batch row
  float vbhr = bhr[frow], vbhz = bhz[frow], vbhn = bhn[frow];

  float hprev[4];
  #pragma unroll
  for (int j = 0; j < 4; ++j) hprev[j] = h0[(size_t)(brow + j) * NH + frow];

  char* hbytes = (char*)hImg;
  int r = tid >> 4, ci = tid & 15;              // staging coords (WG-wide)
  int rb = l & 15, fo = l >> 4;                 // publish coords (wave-local)
  int gidx = fg * 16 + w * 4 + fo;              // this lane's u64 granule index in a row
  char* myT = hl + 65536 + w * 640;             // wave-private 16x16 transpose tile (40B rows)

  for (int s = 0; s < NS; ++s){
    // initial poll loads: these double as the h data loads
    const u64* hsrc = (const u64*)(hbytes + (size_t)(s & 3) * 131072)
                      + (size_t)(bg * 16 + r) * 256 + ci;
    u64 hv[16];
    #pragma unroll
    for (int e = 0; e < 16; ++e) hv[e] = ald8(hsrc + e * 16);

    // x loads (independent of h) overlap the poll
    u64 xrv, xzv, xnv;
    {
      size_t xo = ((size_t)s * NH + frow) * NB + brow;
      xrv = *(const u64*)(xr + xo);
      xzv = *(const u64*)(xz + xo);
      xnv = *(const u64*)(xn + xo);
    }

    // spin: reload only granules still showing the sentinel
    for (;;){
      bool ok = true;
      #pragma unroll
      for (int e = 0; e < 16; ++e) ok &= (hv[e] != SENT);
      if (ok) break;
      #pragma unroll
      for (int e = 0; e < 16; ++e)
        if (hv[e] == SENT) hv[e] = ald8(hsrc + e * 16);
    }

    // stage h slice into LDS (parity s&1), XOR-swizzled for the MFMA reads
    {
      char* dst = hl + (s & 1) * 32768 + r * 2048;
      #pragma unroll
      for (int e = 0; e < 16; ++e)
        *(u64*)(dst + ((e * 128 + ci * 8) ^ ((r & 7) << 4))) = hv[e];
    }
    // re-clear own granules of buffer (s-1)&3 (all waves of this bg have
    // provably finished reading it, since the step-s poll passed)
    if (s >= 1){
      u64* cdst = (u64*)(hbytes + (size_t)((s - 1) & 3) * 131072)
                  + (size_t)(bg * 16 + rb) * 256 + gidx;
      ast8(cdst, SENT);
    }
    __syncthreads();

    // MFMA: acc[b16][f16] per gate, K=1024, even/odd chains
    const char* hb0 = hl + (s & 1) * 32768;
    f32x4 ar0 = (f32x4)0.0f, ar1 = (f32x4)0.0f;
    f32x4 az0 = (f32x4)0.0f, az1 = (f32x4)0.0f;
    f32x4 an0 = (f32x4)0.0f, an1 = (f32x4)0.0f;
    #pragma unroll
    for (int kc = 0; kc < 32; kc += 2){
      short8 a0 = *(const short8*)(hb0 + c * 2048 + ((kc * 64 + q * 16) ^ ((c & 7) << 4)));
      short8 a1 = *(const short8*)(hb0 + c * 2048 + (((kc + 1) * 64 + q * 16) ^ ((c & 7) << 4)));
      ar0 = __builtin_amdgcn_mfma_f32_16x16x32_bf16(a0, bw[0][kc], ar0, 0, 0, 0);
      az0 = __builtin_amdgcn_mfma_f32_16x16x32_bf16(a0, bw[1][kc], az0, 0, 0, 0);
      an0 = __builtin_amdgcn_mfma_f32_16x16x32_bf16(a0, bw[2][kc], an0, 0, 0, 0);
      ar1 = __builtin_amdgcn_mfma_f32_16x16x32_bf16(a1, bw[0][kc + 1], ar1, 0, 0, 0);
      az1 = __builtin_amdgcn_mfma_f32_16x16x32_bf16(a1, bw[1][kc + 1], az1, 0, 0, 0);
      an1 = __builtin_amdgcn_mfma_f32_16x16x32_bf16(a1, bw[2][kc + 1], an1, 0, 0, 0);
    }
    f32x4 ar = ar0 + ar1, az = az0 + az1, an = an0 + an1;

    // combine; h state carried in f32 regs; wave-private transpose tile
    float hn4[4];
    #pragma unroll
    for (int j = 0; j < 4; ++j){
      float rv = sigm(ar[j] + bf2f((u16)(xrv >> (16 * j))) + vbhr);
      float zv = sigm(az[j] + bf2f((u16)(xzv >> (16 * j))) + vbhz);
      float nv = tanhf_(bf2f((u16)(xnv >> (16 * j))) + rv * (an[j] + vbhn));
      float hn = (1.0f - zv) * nv + zv * hprev[j];
      hprev[j] = hn;
      hn4[j] = hn;
      *(u16*)(myT + (q * 4 + j) * 40 + c * 2) = f2bf(hn);
    }
    // wave-local publish: no barrier, no drain, no flag — the stored value is
    // its own readiness signal (never equals SENT since |h| <= 1)
    {
      u64 tv = *(const u64*)(myT + rb * 40 + fo * 8);
      u64* hdst = (u64*)(hbytes + (size_t)((s + 1) & 3) * 131072)
                  + (size_t)(bg * 16 + rb) * 256 + gidx;
      ast8(hdst, tv);
    }
    // out stores after the publish (off the critical path)
    #pragma unroll
    for (int j = 0; j < 4; ++j)
      out[((size_t)(brow + j) * NS + s) * NH + frow] = hn4[j];
  }
  // final hidden state
  #pragma unroll
  for (int j = 0; j < 4; ++j)
    out[(size_t)NB * NS * NH + (size_t)(brow + j) * NH + frow] = hprev[j];
}

// ---------------- launcher ----------------
extern "C" void kernel_launch(void* const* d_in, const int* in_sizes, int n_in,
                              void* d_out, int out_size, void* d_ws, size_t ws_size,
                              hipStream_t stream){
  const float* inputs = (const float*)d_in[0];
  const float* hidden = (const float*)d_in[1];
  const float* w_ir = (const float*)d_in[2];
  const float* w_iz = (const float*)d_in[3];
  const float* w_in = (const float*)d_in[4];
  const float* b_ir = (const float*)d_in[5];
  const float* b_iz = (const float*)d_in[6];
  const float* b_in = (const float*)d_in[7];
  const float* w_hr = (const float*)d_in[8];
  const float* w_hz = (const float*)d_in[9];
  const float* w_hn = (const float*)d_in[10];
  const float* b_hr = (const float*)d_in[11];
  const float* b_hz = (const float*)d_in[12];
  const float* b_hn = (const float*)d_in[13];

  char* ws = (char*)d_ws;
  u16* AT = (u16*)(ws + OFF_AT);
  u16* WI = (u16*)(ws + OFF_WI);
  u16* WH = (u16*)(ws + OFF_WH);
  u16* XR = (u16*)(ws + OFF_XR);
  u16* XZ = (u16*)(ws + OFF_XZ);
  u16* XN = (u16*)(ws + OFF_XN);
  u16* HIMG = (u16*)(ws + OFF_H);
  float* out = (float*)d_out;

  GRU_prep_at<<<dim3(8192), dim3(256), 0, stream>>>(inputs, AT);
  GRU_prep_wi<<<dim3(768), dim3(256), 0, stream>>>(w_ir, w_iz, w_in, WI);
  GRU_prep_wh<<<dim3(1536), dim3(256), 0, stream>>>(w_hr, w_hz, w_hn, WH);
  GRU_xproj<<<dim3(256, 8, 3), dim3(256), 0, stream>>>(AT, WI, b_ir, b_iz, b_in, XR, XZ, XN);
  GRU_init_h<<<dim3(32), dim3(256), 0, stream>>>(hidden, HIMG);   // after xproj: HIMG aliases AT
  GRU_rec<<<dim3(64), dim3(256), 0, stream>>>(WH, XR, XZ, XN, b_hr, b_hz, b_hn,
                                              hidden, HIMG, out);
}